// Round 12
// baseline (4560.703 us; speedup 1.0000x reference)
//
#include <hip/hip_runtime.h>
#include <hip/hip_fp16.h>

#define NN 200000
#define EE 3200000
#define HID 32
#define HB 16384   // src-degree histogram bins per group (64 KB LDS)
#define HG 13      // bin groups: 13*16384 >= NN
#define HBK 25     // edge slices for degree hist
#define ESL (EE / HBK)

#define TN 64                 // dst-tile nodes
#define NT 3125               // NN / 64 exactly
#define CAP 1280              // fixed slots/tile (avg 1024, +8 sigma)
#define KSL 200               // build slices
#define KESL (EE / KSL)       // 16000

#define CNB 64                // nodes per cheb block
#define CST 68                // cheb LDS row stride (16B-aligned, bank-rotating)

// ---------------- fp16 pack helpers (4 halfs <-> float4, 8B memory op) ------

__device__ inline float4 ld_h4(const __half* p) {
    uint2 u = *reinterpret_cast<const uint2*>(p);
    __half2 a = *reinterpret_cast<__half2*>(&u.x);
    __half2 b = *reinterpret_cast<__half2*>(&u.y);
    float2 fa = __half22float2(a), fb = __half22float2(b);
    return make_float4(fa.x, fa.y, fb.x, fb.y);
}

__device__ inline void st_h4(__half* p, float4 v) {
    __half2 a = __floats2half2_rn(v.x, v.y);
    __half2 b = __floats2half2_rn(v.z, v.w);
    uint2 u;
    u.x = *reinterpret_cast<unsigned*>(&a);
    u.y = *reinterpret_cast<unsigned*>(&b);
    *reinterpret_cast<uint2*>(p) = u;
}

// ---------------- src-degree histogram (for dinv; no device atomics) --------

__global__ __launch_bounds__(256) void k_hist(const int* __restrict__ vals,
                                              int* __restrict__ partial) {
    __shared__ int h[HB];
    int b = blockIdx.x / HG, g = blockIdx.x % HG;
    int base = g * HB;
    for (int i = threadIdx.x; i < HB; i += 256) h[i] = 0;
    __syncthreads();
    const int4* p4 = reinterpret_cast<const int4*>(vals + (size_t)b * ESL);
    for (int i = threadIdx.x; i < ESL / 4; i += 256) {
        int4 v = p4[i];
        int a0 = v.x - base, a1 = v.y - base, a2 = v.z - base, a3 = v.w - base;
        if ((unsigned)a0 < HB) atomicAdd(&h[a0], 1);
        if ((unsigned)a1 < HB) atomicAdd(&h[a1], 1);
        if ((unsigned)a2 < HB) atomicAdd(&h[a2], 1);
        if ((unsigned)a3 < HB) atomicAdd(&h[a3], 1);
    }
    __syncthreads();
    int* out = partial + ((size_t)g * HBK + b) * HB;
    for (int i = threadIdx.x; i < HB; i += 256) out[i] = h[i];
}

__global__ void k_hreduce(const int* __restrict__ partial, int* __restrict__ out) {
    int bi = blockIdx.x * 256 + threadIdx.x;
    if (bi >= NN) return;
    int g = bi >> 14, i = bi & (HB - 1);
    const int* p = partial + (size_t)g * HBK * HB + i;
    int s = 0;
#pragma unroll
    for (int b = 0; b < HBK; b++) s += p[(size_t)b << 14];
    out[bi] = s;
}

__global__ void k_dinv(const int* __restrict__ dsrc, float* __restrict__ dinv,
                       float* __restrict__ rdinv) {
    int i = blockIdx.x * 256 + threadIdx.x;
    if (i < NN) {
        int d = dsrc[i];
        float dv = d > 0 ? rsqrtf((float)d) : 0.f;
        dinv[i] = dv;
        rdinv[i] = d > 0 ? 1.f / dv : 0.f;   // sqrt(deg)
    }
}

// ---------------- one-kernel bucket build (fixed-capacity tiles) ------------

__global__ __launch_bounds__(256) void k_build1(const int* __restrict__ ei,
                                                int* __restrict__ gcnt,
                                                int* __restrict__ ebkt) {
    __shared__ int h[NT];
    for (int i = threadIdx.x; i < NT; i += 256) h[i] = 0;
    __syncthreads();
    int base = blockIdx.x * KESL;
    for (int i = threadIdx.x; i < KESL; i += 256)
        atomicAdd(&h[ei[EE + base + i] >> 6], 1);
    __syncthreads();
    for (int i = threadIdx.x; i < NT; i += 256) {
        int c = h[i];
        h[i] = (c > 0) ? atomicAdd(&gcnt[i], c) : 0;   // tile-relative base
    }
    __syncthreads();
    for (int i = threadIdx.x; i < KESL; i += 256) {
        int e = base + i;
        int src = ei[e], dst = ei[EE + e];
        int key = dst >> 6;
        int pos = atomicAdd(&h[key], 1);
        if (pos < CAP)
            ebkt[key * CAP + pos] = (src << 6) | (dst & 63);
    }
}

// ---------------- per-tile LDS counting sort -> per-node ranges + csr -------

__global__ __launch_bounds__(256) void k_fill2(const int* __restrict__ gcnt,
                                               const int* __restrict__ ebkt,
                                               int2* __restrict__ rowse,
                                               int* __restrict__ csr) {
    __shared__ int deg[TN], excl[TN], rank[TN];
    __shared__ int buf[CAP];
    int k = blockIdx.x, tid = threadIdx.x;
    int cnt = min(gcnt[k], CAP);
    int base = k * CAP;
    if (tid < TN) { deg[tid] = 0; rank[tid] = 0; }
    __syncthreads();
    for (int j = tid; j < cnt; j += 256)
        atomicAdd(&deg[ebkt[base + j] & 63], 1);
    __syncthreads();
    if (tid == 0) {
        int s = 0;
#pragma unroll
        for (int i = 0; i < TN; i++) { excl[i] = s; s += deg[i]; }
    }
    __syncthreads();
    if (tid < TN)
        rowse[k * TN + tid] = make_int2(base + excl[tid],
                                        base + excl[tid] + deg[tid]);
    for (int j = tid; j < cnt; j += 256) {
        int e = ebkt[base + j];
        int l = e & 63;
        int r = atomicAdd(&rank[l], 1);
        buf[excl[l] + r] = e >> 6;
    }
    __syncthreads();
    for (int j = tid; j < cnt; j += 256) csr[base + j] = buf[j];
}

// ---------------- input MLP: unscaled + scaled fp16 outputs -----------------

__global__ void k_mlp0(const float* __restrict__ x, const float* __restrict__ W0,
                       const float* __restrict__ b0, const float* __restrict__ dinv,
                       __half* __restrict__ outU, __half* __restrict__ outS) {
    int t = blockIdx.x * 256 + threadIdx.x;   // t = n*32 + o
    int n = t >> 5, o = t & 31;
    if (n < NN) {
        float acc = b0[o];
#pragma unroll
        for (int i = 0; i < 3; i++) acc += x[n * 3 + i] * W0[i * 32 + o];
        acc = fmaxf(acc, 0.f);
        outU[t] = __float2half(acc);
        outS[t] = __float2half(acc * dinv[n]);
    }
}

// ---------------- propagation: pure gather-sum on scaled features -----------
// UNCHANGED from R11 (measure it cleanly in top-5 this round).

__global__ __launch_bounds__(256) void k_prop(const int2* __restrict__ rowse,
                                              const int* __restrict__ csr,
                                              const float* __restrict__ dinv,
                                              const __half* __restrict__ xs,
                                              __half* __restrict__ ys) {
    int t = blockIdx.x * 256 + threadIdx.x;
    int n = t >> 3, c = t & 7;
    if (n >= NN) return;
    int2 se = rowse[n];
    int j = se.x, end = se.y;
    float4 acc = make_float4(0.f, 0.f, 0.f, 0.f);
    const __half* xc = xs + (size_t)c * 4;
    for (; j + 8 <= end; j += 8) {
        int s0 = csr[j + 0], s1 = csr[j + 1], s2 = csr[j + 2], s3 = csr[j + 3];
        int s4 = csr[j + 4], s5 = csr[j + 5], s6 = csr[j + 6], s7 = csr[j + 7];
        float4 v0 = ld_h4(xc + (size_t)s0 * 32);
        float4 v1 = ld_h4(xc + (size_t)s1 * 32);
        float4 v2 = ld_h4(xc + (size_t)s2 * 32);
        float4 v3 = ld_h4(xc + (size_t)s3 * 32);
        float4 v4 = ld_h4(xc + (size_t)s4 * 32);
        float4 v5 = ld_h4(xc + (size_t)s5 * 32);
        float4 v6 = ld_h4(xc + (size_t)s6 * 32);
        float4 v7 = ld_h4(xc + (size_t)s7 * 32);
        acc.x += (v0.x + v1.x) + (v2.x + v3.x) + (v4.x + v5.x) + (v6.x + v7.x);
        acc.y += (v0.y + v1.y) + (v2.y + v3.y) + (v4.y + v5.y) + (v6.y + v7.y);
        acc.z += (v0.z + v1.z) + (v2.z + v3.z) + (v4.z + v5.z) + (v6.z + v7.z);
        acc.w += (v0.w + v1.w) + (v2.w + v3.w) + (v4.w + v5.w) + (v6.w + v7.w);
    }
    for (; j + 4 <= end; j += 4) {
        int s0 = csr[j + 0], s1 = csr[j + 1], s2 = csr[j + 2], s3 = csr[j + 3];
        float4 v0 = ld_h4(xc + (size_t)s0 * 32);
        float4 v1 = ld_h4(xc + (size_t)s1 * 32);
        float4 v2 = ld_h4(xc + (size_t)s2 * 32);
        float4 v3 = ld_h4(xc + (size_t)s3 * 32);
        acc.x += (v0.x + v1.x) + (v2.x + v3.x);
        acc.y += (v0.y + v1.y) + (v2.y + v3.y);
        acc.z += (v0.z + v1.z) + (v2.z + v3.z);
        acc.w += (v0.w + v1.w) + (v2.w + v3.w);
    }
    for (; j < end; j++) {
        float4 v = ld_h4(xc + (size_t)csr[j] * 32);
        acc.x += v.x; acc.y += v.y; acc.z += v.z; acc.w += v.w;
    }
    float dv = dinv[n];
    float m = -dv * dv;
    st_h4(ys + (size_t)n * 32 + c * 4,
          make_float4(m * acc.x, m * acc.y, m * acc.z, m * acc.w));
}

// ---------------- fused Cheb combine, W-amortized (R12) ---------------------
// 64 nodes/block; thread (o, node-group of 8). LDS: Wa=W0-W2, W1, W2 (12KB) +
// transposed features [chan][node] (T0, rv*P1, 2rv*P2). Inner loop: 3 W reads
// amortized over 8 nodes via ds_read_b128 feature loads.
// out = relu?(T0@W0 + T1@W1 + (2*T2raw - T0)@W2 + b [+res])
//     = relu?(T0@Wa + (rv*P1)@W1 + (2rv*P2)@W2 + b [+res])

__global__ __launch_bounds__(256) void k_cheb(const __half* __restrict__ T0u,
        const __half* __restrict__ P1s, const __half* __restrict__ P2s,
        const __half* __restrict__ resu, __half* __restrict__ outU,
        __half* __restrict__ outS,
        const float* __restrict__ dinv, const float* __restrict__ rdinv,
        const float* __restrict__ W, const float* __restrict__ b,
        int do_relu, int has_res) {
    __shared__ float sT0[32][CST], sP1[32][CST], sP2[32][CST];
    __shared__ float sWa[1024], sW1[1024], sW2[1024];
    int tid = threadIdx.x;
    int n0 = blockIdx.x * CNB;
    // stage weights (fold W0-W2)
    for (int i = tid; i < 1024; i += 256) {
        float w0 = W[i], w1 = W[1024 + i], w2 = W[2048 + i];
        sWa[i] = w0 - w2;
        sW1[i] = w1;
        sW2[i] = w2;
    }
    // stage features transposed: thread (n = tid&31, cg = tid>>5), 2 passes
    {
        int n = tid & 31, cg = tid >> 5;
        int cb = cg * 4;
#pragma unroll
        for (int p = 0; p < 2; p++) {
            int nn = n + p * 32;
            int g = (n0 + nn) * 32 + cb;
            float rv = rdinv[n0 + nn];
            float4 t0 = ld_h4(T0u + g);
            float4 p1 = ld_h4(P1s + g);
            float4 p2 = ld_h4(P2s + g);
            sT0[cb + 0][nn] = t0.x; sT0[cb + 1][nn] = t0.y;
            sT0[cb + 2][nn] = t0.z; sT0[cb + 3][nn] = t0.w;
            sP1[cb + 0][nn] = p1.x * rv; sP1[cb + 1][nn] = p1.y * rv;
            sP1[cb + 2][nn] = p1.z * rv; sP1[cb + 3][nn] = p1.w * rv;
            float r2 = 2.f * rv;
            sP2[cb + 0][nn] = p2.x * r2; sP2[cb + 1][nn] = p2.y * r2;
            sP2[cb + 2][nn] = p2.z * r2; sP2[cb + 3][nn] = p2.w * r2;
        }
    }
    __syncthreads();
    int o = tid & 31, ng = tid >> 5;   // node group: nodes ng*8 .. ng*8+7
    int nb = ng * 8;
    float acc[8];
    float bb = b[o];
#pragma unroll
    for (int nd = 0; nd < 8; nd++) acc[nd] = bb;
#pragma unroll
    for (int i = 0; i < 32; i++) {
        float wa = sWa[i * 32 + o], w1 = sW1[i * 32 + o], w2 = sW2[i * 32 + o];
        float4 ta = *reinterpret_cast<const float4*>(&sT0[i][nb]);
        float4 tb = *reinterpret_cast<const float4*>(&sT0[i][nb + 4]);
        float4 pa = *reinterpret_cast<const float4*>(&sP1[i][nb]);
        float4 pb = *reinterpret_cast<const float4*>(&sP1[i][nb + 4]);
        float4 qa = *reinterpret_cast<const float4*>(&sP2[i][nb]);
        float4 qb = *reinterpret_cast<const float4*>(&sP2[i][nb + 4]);
        acc[0] += ta.x * wa + pa.x * w1 + qa.x * w2;
        acc[1] += ta.y * wa + pa.y * w1 + qa.y * w2;
        acc[2] += ta.z * wa + pa.z * w1 + qa.z * w2;
        acc[3] += ta.w * wa + pa.w * w1 + qa.w * w2;
        acc[4] += tb.x * wa + pb.x * w1 + qb.x * w2;
        acc[5] += tb.y * wa + pb.y * w1 + qb.y * w2;
        acc[6] += tb.z * wa + pb.z * w1 + qb.z * w2;
        acc[7] += tb.w * wa + pb.w * w1 + qb.w * w2;
    }
#pragma unroll
    for (int nd = 0; nd < 8; nd++) {
        int nn = nb + nd;
        int g = (n0 + nn) * 32 + o;
        float a = acc[nd];
        if (has_res) a += __half2float(resu[g]);
        if (do_relu) a = fmaxf(a, 0.f);
        outU[g] = __float2half(a);
        outS[g] = __float2half(a * dinv[n0 + nn]);
    }
}

// ---------------- final head: out = X @ W1 + b1 (fp16 in, fp32 out) ---------

__global__ void k_final(const __half* __restrict__ X, const float* __restrict__ W1,
                        const float* __restrict__ b1, float* __restrict__ out) {
    int n = blockIdx.x * 256 + threadIdx.x;
    if (n < NN) {
        float acc = b1[0];
        const __half* xp = X + (size_t)n * 32;
#pragma unroll
        for (int c = 0; c < 8; c++) {
            float4 v = ld_h4(xp + c * 4);
            acc += v.x * W1[c * 4 + 0] + v.y * W1[c * 4 + 1] +
                   v.z * W1[c * 4 + 2] + v.w * W1[c * 4 + 3];
        }
        out[n] = acc;
    }
}

extern "C" void kernel_launch(void* const* d_in, const int* in_sizes, int n_in,
                              void* d_out, int out_size, void* d_ws, size_t ws_size,
                              hipStream_t stream) {
    const float* x    = (const float*)d_in[0];
    const int*   ei   = (const int*)d_in[1];
    const float* W0   = (const float*)d_in[2];
    const float* b0   = (const float*)d_in[3];
    const float* c11W = (const float*)d_in[4];
    const float* c11b = (const float*)d_in[5];
    const float* c12W = (const float*)d_in[6];
    const float* c12b = (const float*)d_in[7];
    const float* c21W = (const float*)d_in[8];
    const float* c21b = (const float*)d_in[9];
    const float* c22W = (const float*)d_in[10];
    const float* c22b = (const float*)d_in[11];
    const float* W1   = (const float*)d_in[12];
    const float* b1   = (const float*)d_in[13];
    float* out = (float*)d_out;

    char* ws = (char*)d_ws;
    int* dsrc = (int*)ws;     ws += (size_t)NN * 4;
    float* dinv = (float*)ws; ws += (size_t)NN * 4;
    float* rdinv = (float*)ws; ws += (size_t)NN * 4;
    int* gcnt = (int*)ws;     ws += (size_t)NT * 4;      // memset target
    int* partial = (int*)ws;  ws += (size_t)HG * HBK * HB * 4;   // 21.3 MB
    int* ebkt = (int*)ws;     ws += (size_t)NT * CAP * 4;        // 16 MB
    int* csr = (int*)ws;      ws += (size_t)NT * CAP * 4;        // 16 MB
    ws = (char*)(((uintptr_t)ws + 15) & ~(uintptr_t)15);
    int2* rowse = (int2*)ws;  ws += (size_t)NN * 8;              // 1.6 MB
    __half* F0u = (__half*)ws; ws += (size_t)NN * HID * 2;
    __half* F0s = (__half*)ws; ws += (size_t)NN * HID * 2;
    __half* F1u = (__half*)ws; ws += (size_t)NN * HID * 2;
    __half* F1s = (__half*)ws; ws += (size_t)NN * HID * 2;
    __half* P1s = (__half*)ws; ws += (size_t)NN * HID * 2;
    __half* P2s = (__half*)ws; ws += (size_t)NN * HID * 2;

    hipMemsetAsync(gcnt, 0, (size_t)NT * 4, stream);

    // src degrees -> dinv, rdinv
    k_hist<<<HG * HBK, 256, 0, stream>>>(ei, partial);
    k_hreduce<<<(NN + 255) / 256, 256, 0, stream>>>(partial, dsrc);
    k_dinv<<<(NN + 255) / 256, 256, 0, stream>>>(dsrc, dinv, rdinv);

    // bucket build + per-node CSR (4B src-only entries)
    k_build1<<<KSL, 256, 0, stream>>>(ei, gcnt, ebkt);
    k_fill2<<<NT, 256, 0, stream>>>(gcnt, ebkt, rowse, csr);

    k_mlp0<<<NN * HID / 256, 256, 0, stream>>>(x, W0, b0, dinv, F0u, F0s);

    auto conv = [&](const __half* T0u, const __half* T0s, const __half* resu,
                    __half* oU, __half* oS,
                    const float* W, const float* b, int relu, int has_res) {
        k_prop<<<NN * 8 / 256, 256, 0, stream>>>(rowse, csr, dinv, T0s, P1s);
        k_prop<<<NN * 8 / 256, 256, 0, stream>>>(rowse, csr, dinv, P1s, P2s);
        k_cheb<<<NN / CNB, 256, 0, stream>>>(T0u, P1s, P2s, resu, oU, oS,
                                             dinv, rdinv, W, b, relu, has_res);
    };

    conv(F0u, F0s, nullptr, F1u, F1s, c11W, c11b, 1, 0);  // blk1 conv1
    conv(F1u, F1s, F0u,     F0u, F0s, c12W, c12b, 1, 1);  // blk1 conv2 (+res)
    conv(F0u, F0s, nullptr, F1u, F1s, c21W, c21b, 1, 0);  // blk2 conv1
    conv(F1u, F1s, F0u,     F0u, F0s, c22W, c22b, 1, 1);  // blk2 conv2 (+res)

    k_final<<<(NN + 255) / 256, 256, 0, stream>>>(F0u, W1, b1, out);
}